// Round 16
// baseline (239.618 us; speedup 1.0000x reference)
//
#include <hip/hip_runtime.h>
#include <hip/hip_bf16.h>

// Problem constants (from reference)
#define FEAT 64          // IN_F = HID_F = OUT_F
#define CAT_F 128        // HID_F + IN_F
#define CAP   64         // ELL capacity; deg ~ Poisson(10), P(deg>64) ~ 0

// bf16 helpers
__device__ inline float blo(unsigned u) { union { unsigned x; float f; } v; v.x = u << 16; return v.f; }
__device__ inline unsigned short f2b(float f) {
    union { float f; unsigned u; } v; v.f = f;
    unsigned r = v.u + 0x7FFFu + ((v.u >> 16) & 1u);
    return (unsigned short)(r >> 16);
}

// ---------------------------------------------------------------------------
// batch convert + root boundaries; int64/int32 mode detected per-block from
// the edge buffer (high words of random edge ids are 0 iff int64).
__global__ void batch_prep(const void* __restrict__ bt, const unsigned* __restrict__ ei_u,
                           int* __restrict__ batch32, int* __restrict__ root_idx,
                           int N, int G) {
    __shared__ int smode;
    if (threadIdx.x == 0)
        smode = (ei_u[1] == 0u && ei_u[3] == 0u && ei_u[5] == 0u && ei_u[7] == 0u) ? 1 : 0;
    __syncthreads();
    int i = blockIdx.x * blockDim.x + threadIdx.x;
    if (i >= N) return;
    int m = smode;
    int b = m ? (int)((const long long*)bt)[i] : ((const int*)bt)[i];
    batch32[i] = b;
    if (i == 0) { root_idx[0] = 0; root_idx[G] = N; }
    else {
        int bp = m ? (int)((const long long*)bt)[i - 1] : ((const int*)bt)[i - 1];
        if (b != bp) root_idx[b] = i;
    }
}

// Fused degree-count + ELL adjacency build. STANDALONE (rounds 12-14 lesson:
// co-running gemm with this atomic phase degrades the atomics more than the
// hidden gemm gains). Floor: 2M atomics + 1M scattered 4B stores -> ~91 MB
// write-through at ~920 GB/s ~= 105 us.
__global__ void ell_build(const void* __restrict__ ei,
                          int* __restrict__ deg_cnt, int* __restrict__ cnt_col,
                          int* __restrict__ ell, int E) {
    __shared__ int smode;
    if (threadIdx.x == 0) {
        const unsigned* u = (const unsigned*)ei;
        smode = (u[1] == 0u && u[3] == 0u && u[5] == 0u && u[7] == 0u) ? 1 : 0;
    }
    __syncthreads();
    int e = blockIdx.x * blockDim.x + threadIdx.x;
    if (e >= E) return;
    int r, c;
    if (smode) {
        const long long* p = (const long long*)ei;
        r = (int)p[e]; c = (int)p[E + e];
    } else {
        const int* p = (const int*)ei;
        r = p[e]; c = p[E + e];
    }
    if (r != c) {
        atomicAdd(&deg_cnt[r], 1);
        int slot = atomicAdd(&cnt_col[c], 1);
        if (slot < CAP) ell[c * CAP + slot] = r;
    }
}

// merged [dis blocks | rootc blocks]:
//   dis[i] = (1+deg)^-1/2 ;  rootc[g] = relu(x[root_g]) @ w2[64:128]
__global__ void dis_rootc(const int* __restrict__ deg_cnt, float* __restrict__ dis, int N,
                          const float* __restrict__ x, const float* __restrict__ w2hi,
                          const int* __restrict__ root_idx, float* __restrict__ rootc,
                          int G, int nb) {
    int bid = blockIdx.x;
    if (bid < nb) {
        int i = bid * 256 + threadIdx.x;
        if (i < N) dis[i] = rsqrtf(1.0f + (float)deg_cnt[i]);
        return;
    }
    int g = ((bid - nb) * 256 + threadIdx.x) >> 6;
    int f = threadIdx.x & 63;
    if (g >= G) return;
    const float* xr = x + (long)root_idx[g] * 64;
    float acc = 0.f;
#pragma unroll
    for (int k = 0; k < 64; ++k)
        acc = fmaf(fmaxf(xr[k], 0.f), w2hi[k * 64 + f], acc);
    rootc[(long)g * 64 + f] = acc;
}

// ---------------------------------------------------------------------------
// gemm1 (round-10 proven monolith): hs[row] = bf16( dis[row] * (x[row] @ w1) )
// 64x64 tile, 256 threads, 4x4 micro-tile, single barrier, LDS inside,
// named float4 locals, __launch_bounds__(256,4). NO k-split (round-13 lesson).
__global__ __launch_bounds__(256, 4)
void gemm1_kernel(const float* __restrict__ A, const float* __restrict__ B,
                  const float* __restrict__ dis, unsigned short* __restrict__ hs, int N) {
    __shared__ float AsT[64][68];   // [k][row]
    __shared__ float Bs[64][64];    // [k][col]
    const int tid = threadIdx.x;
    const long base = (long)blockIdx.x * 64;

#pragma unroll
    for (int u = 0; u < 4; ++u) {
        int v   = tid + u * 256;
        int row = v >> 4;
        int c4  = (v & 15) * 4;
        float4 bv = *(const float4*)&B[row * 64 + c4];
        *(float4*)&Bs[row][c4] = bv;
        float4 av = make_float4(0.f, 0.f, 0.f, 0.f);
        if (base + row < N) av = *(const float4*)&A[(base + row) * 64 + c4];
        AsT[c4 + 0][row] = av.x;
        AsT[c4 + 1][row] = av.y;
        AsT[c4 + 2][row] = av.z;
        AsT[c4 + 3][row] = av.w;
    }
    __syncthreads();

    const int c0 = (tid & 15) * 4;
    const int r0 = (tid >> 4) * 4;
    float4 acc0 = make_float4(0.f, 0.f, 0.f, 0.f);
    float4 acc1 = acc0, acc2 = acc0, acc3 = acc0;

#pragma unroll 4
    for (int k = 0; k < 64; ++k) {
        float4 bv = *(const float4*)&Bs[k][c0];
        float4 av = *(const float4*)&AsT[k][r0];
        acc0.x = fmaf(av.x, bv.x, acc0.x); acc0.y = fmaf(av.x, bv.y, acc0.y);
        acc0.z = fmaf(av.x, bv.z, acc0.z); acc0.w = fmaf(av.x, bv.w, acc0.w);
        acc1.x = fmaf(av.y, bv.x, acc1.x); acc1.y = fmaf(av.y, bv.y, acc1.y);
        acc1.z = fmaf(av.y, bv.z, acc1.z); acc1.w = fmaf(av.y, bv.w, acc1.w);
        acc2.x = fmaf(av.z, bv.x, acc2.x); acc2.y = fmaf(av.z, bv.y, acc2.y);
        acc2.z = fmaf(av.z, bv.z, acc2.z); acc2.w = fmaf(av.z, bv.w, acc2.w);
        acc3.x = fmaf(av.w, bv.x, acc3.x); acc3.y = fmaf(av.w, bv.y, acc3.y);
        acc3.z = fmaf(av.w, bv.z, acc3.z); acc3.w = fmaf(av.w, bv.w, acc3.w);
    }

#define STORE_ROW(i, a)                                                       \
    {                                                                         \
        long row = base + r0 + (i);                                           \
        if (row < N) {                                                        \
            float s = dis[row];                                               \
            ushort4 o;                                                        \
            o.x = f2b(s * a.x); o.y = f2b(s * a.y);                           \
            o.z = f2b(s * a.z); o.w = f2b(s * a.w);                           \
            *(ushort4*)&hs[row * 64 + c0] = o;                                \
        }                                                                     \
    }
    STORE_ROW(0, acc0)
    STORE_ROW(1, acc1)
    STORE_ROW(2, acc2)
    STORE_ROW(3, acc3)
#undef STORE_ROW
}

// gemm2 (round-14 validated): hs[row] = bf16( dis[row]*(relu(x2b[row]) @ B + rootc[batch]) )
__global__ __launch_bounds__(256, 4)
void gemm2_kernel(const unsigned short* __restrict__ x2b, const float* __restrict__ B,
                  const float* __restrict__ addv, const int* __restrict__ batch32,
                  const float* __restrict__ dis, unsigned short* __restrict__ hs, int N) {
    __shared__ float AsT[64][68];
    __shared__ float Bs[64][64];
    const int tid = threadIdx.x;
    const long base = (long)blockIdx.x * 64;

#pragma unroll
    for (int u = 0; u < 4; ++u) {
        int v   = tid + u * 256;
        int row = v >> 4;
        int c4  = (v & 15) * 4;
        float4 bv = *(const float4*)&B[row * 64 + c4];
        *(float4*)&Bs[row][c4] = bv;
        float a0 = 0.f, a1 = 0.f, a2 = 0.f, a3 = 0.f;
        if (base + row < N) {
            ushort4 o = *(const ushort4*)&x2b[(base + row) * 64 + c4];
            a0 = blo(o.x); a1 = blo(o.y); a2 = blo(o.z); a3 = blo(o.w);
        }
        AsT[c4 + 0][row] = fmaxf(a0, 0.f);
        AsT[c4 + 1][row] = fmaxf(a1, 0.f);
        AsT[c4 + 2][row] = fmaxf(a2, 0.f);
        AsT[c4 + 3][row] = fmaxf(a3, 0.f);
    }
    __syncthreads();

    const int c0 = (tid & 15) * 4;
    const int r0 = (tid >> 4) * 4;
    float4 acc0 = make_float4(0.f, 0.f, 0.f, 0.f);
    float4 acc1 = acc0, acc2 = acc0, acc3 = acc0;

#pragma unroll 4
    for (int k = 0; k < 64; ++k) {
        float4 bv = *(const float4*)&Bs[k][c0];
        float4 av = *(const float4*)&AsT[k][r0];
        acc0.x = fmaf(av.x, bv.x, acc0.x); acc0.y = fmaf(av.x, bv.y, acc0.y);
        acc0.z = fmaf(av.x, bv.z, acc0.z); acc0.w = fmaf(av.x, bv.w, acc0.w);
        acc1.x = fmaf(av.y, bv.x, acc1.x); acc1.y = fmaf(av.y, bv.y, acc1.y);
        acc1.z = fmaf(av.y, bv.z, acc1.z); acc1.w = fmaf(av.y, bv.w, acc1.w);
        acc2.x = fmaf(av.z, bv.x, acc2.x); acc2.y = fmaf(av.z, bv.y, acc2.y);
        acc2.z = fmaf(av.z, bv.z, acc2.z); acc2.w = fmaf(av.z, bv.w, acc2.w);
        acc3.x = fmaf(av.w, bv.x, acc3.x); acc3.y = fmaf(av.w, bv.y, acc3.y);
        acc3.z = fmaf(av.w, bv.z, acc3.z); acc3.w = fmaf(av.w, bv.w, acc3.w);
    }

#define STORE_ROW(i, a)                                                       \
    {                                                                         \
        long row = base + r0 + (i);                                           \
        if (row < N) {                                                        \
            int g = batch32[row];                                             \
            float4 adv = *(const float4*)&addv[(long)g * 64 + c0];            \
            a.x += adv.x; a.y += adv.y; a.z += adv.z; a.w += adv.w;           \
            float s = dis[row];                                               \
            ushort4 o;                                                        \
            o.x = f2b(s * a.x); o.y = f2b(s * a.y);                           \
            o.z = f2b(s * a.z); o.w = f2b(s * a.w);                           \
            *(ushort4*)&hs[row * 64 + c0] = o;                                \
        }                                                                     \
    }
    STORE_ROW(0, acc0)
    STORE_ROW(1, acc1)
    STORE_ROW(2, acc2)
    STORE_ROW(3, acc3)
#undef STORE_ROW
}

// ---------------------------------------------------------------------------
// Per-node gather sum (round-10 proven form): acc[f] = Sum_e hs[row_e][f].
// lane = feature (one 128B wave-load per edge); edge ids pre-loaded once
// (coalesced) and broadcast via __shfl; 4 independent loads in flight.
// (Round-15 lesson: pair-packing loads does NOT help — the limit is L2/fabric
// random-gather transactions, not load-instruction count.)
__device__ inline float gather_sum(const unsigned short* __restrict__ hs,
                                   const int* __restrict__ row, int cnt, int lane) {
    int rv = (lane < cnt) ? row[lane] : 0;
    float acc = 0.f;
    int j = 0;
    for (; j + 4 <= cnt; j += 4) {
        int r0 = __shfl(rv, j,     64);
        int r1 = __shfl(rv, j + 1, 64);
        int r2 = __shfl(rv, j + 2, 64);
        int r3 = __shfl(rv, j + 3, 64);
        float v0 = blo(hs[r0 * 64 + lane]);
        float v1 = blo(hs[r1 * 64 + lane]);
        float v2 = blo(hs[r2 * 64 + lane]);
        float v3 = blo(hs[r3 * 64 + lane]);
        acc += v0; acc += v1; acc += v2; acc += v3;
    }
    for (; j < cnt; ++j) {
        int r = __shfl(rv, j, 64);
        acc += blo(hs[r * 64 + lane]);
    }
    return acc;
}

// conv1 aggregation (prescaled hs), bf16 output:
//   x2b[node][f] = bf16( dis[node]*(Sum_e hs[r][f] + hs[node][f]) + b1[f] )
__global__ void agg1_kernel(const unsigned short* __restrict__ hs, const float* __restrict__ dis,
                            const int* __restrict__ cnt_col, const int* __restrict__ ell,
                            const float* __restrict__ bias, unsigned short* __restrict__ x2b,
                            int N) {
    int node = (blockIdx.x * blockDim.x + threadIdx.x) >> 6;
    int lane = threadIdx.x & 63;
    if (node >= N) return;
    int cnt = min(cnt_col[node], CAP);
    float acc = gather_sum(hs, ell + (long)node * CAP, cnt, lane);
    float dc = dis[node];
    float self = blo(hs[node * 64 + lane]);
    float v = fmaf(dc, acc + self, bias[lane]);
    x2b[(long)node * 64 + lane] = f2b(v);
}

// conv2 aggregation + per-graph mean, atomic epilogue (no final_reduce):
// graph g split into 4 chunks; block (4 waves) per chunk accumulates
//   s[f] = Sum_n relu(dis[n]*(Sum_e hs[r][f] + hs[n][f]) + b2[f])
// then atomicAdd(s[f]/len) into out[g][f]. Chunk 0 writes out[g][64+f]=x2b[root].
// out is zeroed per launch (replay-safe).
__global__ __launch_bounds__(256)
void agg2_kernel(const unsigned short* __restrict__ hs, const float* __restrict__ dis,
                 const int* __restrict__ cnt_col, const int* __restrict__ ell,
                 const float* __restrict__ bias, const int* __restrict__ root_idx,
                 const unsigned short* __restrict__ x2b, float* __restrict__ out) {
    __shared__ float ls[4][64];
    int g  = blockIdx.x >> 2;
    int ch = blockIdx.x & 3;
    int root = root_idx[g], nend = root_idx[g + 1];
    int len = nend - root;
    int chunk = (len + 3) >> 2;
    int start = root + ch * chunk;
    int end   = min(start + chunk, nend);
    int wid  = threadIdx.x >> 6;
    int lane = threadIdx.x & 63;
    float bv = bias[lane];
    float s = 0.f;
    for (int node = start + wid; node < end; node += 4) {
        int cnt = min(cnt_col[node], CAP);
        float acc = gather_sum(hs, ell + (long)node * CAP, cnt, lane);
        float dc = dis[node];
        float self = blo(hs[node * 64 + lane]);
        s += fmaxf(fmaf(dc, acc + self, bv), 0.f);
    }
    ls[wid][lane] = s;
    __syncthreads();
    if (threadIdx.x < 64) {
        int f = threadIdx.x;
        float v = ls[0][f] + ls[1][f] + ls[2][f] + ls[3][f];
        atomicAdd(&out[(long)g * CAT_F + f], v / (float)len);
        if (ch == 0)
            out[(long)g * CAT_F + 64 + f] = blo((unsigned)x2b[(long)root * 64 + f]);
    }
}

// ---------------------------------------------------------------------------
extern "C" void kernel_launch(void* const* d_in, const int* in_sizes, int n_in,
                              void* d_out, int out_size, void* d_ws, size_t ws_size,
                              hipStream_t stream) {
    const float* x  = (const float*)d_in[0];
    const void*  ei = d_in[1];
    const void*  bt = d_in[2];
    const float* w1 = (const float*)d_in[3];
    const float* b1 = (const float*)d_in[4];
    const float* w2 = (const float*)d_in[5];
    const float* b2 = (const float*)d_in[6];
    float* out = (float*)d_out;

    const int N = in_sizes[0] / FEAT;     // 100000
    const int E = in_sizes[1] / 2;        // 1000000
    const int G = out_size / CAT_F;       // 500

    // workspace layout
    char* p = (char*)d_ws;
    size_t off = 0;
    auto alloc = [&](size_t bytes) {
        void* q = p + off;
        off = (off + bytes + 255) & ~(size_t)255;
        return q;
    };
    int*   batch32  = (int*)  alloc((size_t)N * sizeof(int));
    int*   deg_cnt  = (int*)  alloc((size_t)N * sizeof(int));
    float* dis      = (float*)alloc((size_t)N * sizeof(float));
    int*   cnt_col  = (int*)  alloc((size_t)N * sizeof(int));
    int*   ell      = (int*)  alloc((size_t)N * CAP * sizeof(int));
    int*   root_idx = (int*)  alloc((size_t)(G + 1) * sizeof(int));
    float* rootc    = (float*)alloc((size_t)G * FEAT * sizeof(float));
    unsigned short* hs  = (unsigned short*)alloc((size_t)N * FEAT * sizeof(unsigned short));
    unsigned short* x2b = (unsigned short*)alloc((size_t)N * FEAT * sizeof(unsigned short));
    (void)ws_size; (void)n_in;

    hipMemsetAsync(deg_cnt, 0, (size_t)N * sizeof(int), stream);
    hipMemsetAsync(cnt_col, 0, (size_t)N * sizeof(int), stream);
    hipMemsetAsync(out, 0, (size_t)out_size * sizeof(float), stream);

    batch_prep<<<(N + 255) / 256, 256, 0, stream>>>(bt, (const unsigned*)ei,
                                                    batch32, root_idx, N, G);

    // CSR(ELL) build + degrees (standalone — fusion abandoned, r12-r14)
    ell_build<<<(E + 255) / 256, 256, 0, stream>>>(ei, deg_cnt, cnt_col, ell, E);

    // merged [dis | rootc]
    const int nb = (N + 255) / 256;
    const int rb = (G * FEAT + 255) / 256;
    dis_rootc<<<nb + rb, 256, 0, stream>>>(deg_cnt, dis, N,
                                           x, w2 + FEAT * FEAT, root_idx, rootc, G, nb);

    const int gb = (N + 63) / 64;
    const int agg_blocks = (N + 3) / 4;

    // conv1: hs = bf16(dis * (x @ w1)) ; x2b = bf16(agg(hs) + b1)
    gemm1_kernel<<<gb, 256, 0, stream>>>(x, w1, dis, hs, N);
    agg1_kernel<<<agg_blocks, 256, 0, stream>>>(hs, dis, cnt_col, ell, b1, x2b, N);

    // conv2: hs = bf16(dis * (relu(x2b) @ w2lo + rootc[batch]))
    gemm2_kernel<<<gb, 256, 0, stream>>>(x2b, w2, rootc, batch32, dis, hs, N);

    // conv2 aggregation + per-graph mean (atomic epilogue, out pre-zeroed)
    agg2_kernel<<<G * 4, 256, 0, stream>>>(hs, dis, cnt_col, ell, b2, root_idx, x2b, out);
}